// Round 1
// baseline (137.618 us; speedup 1.0000x reference)
//
#include <hip/hip_runtime.h>

typedef _Float16 f16x2 __attribute__((ext_vector_type(2)));
typedef _Float16 f16x8 __attribute__((ext_vector_type(8)));
typedef unsigned short u16x8 __attribute__((ext_vector_type(8)));
typedef float f32x4 __attribute__((ext_vector_type(4)));

#define NS 1024
#define NQ 1024
#define DD 128
#define HH 64
#define NWAY 8
#define SCHUNK 128
#define QPER 8

// Main kernel: for an s-chunk of 128 supports and QPER queries, compute
// sim(q,s) = relu(|q-s| @ W1^T + b1) @ W2 and accumulate per-class sums.
// b2 is dropped: it shifts all logits equally and log_softmax is shift-invariant.
__global__ __launch_bounds__(256, 2) void siamese_main(
    const float* __restrict__ support_x,
    const int* __restrict__ support_y,
    const float* __restrict__ query_x,
    const float* __restrict__ W1,
    const float* __restrict__ b1,
    const float* __restrict__ W2,
    float* __restrict__ class_sums)
{
    // diff stored in MFMA A-fragment order:
    // half index = (s>>4)*2048 + (d>>3)*128 + (s&15)*8 + (d&7)
    __shared__ _Float16 diff[128 * 128];
    __shared__ _Float16 qrow[DD];
    __shared__ int labels[SCHUNK];
    __shared__ float cls[NWAY];

    const int t = threadIdx.x;
    const int wave = t >> 6;
    const int lane = t & 63;
    const int c = lane & 15;     // column / n-index within MFMA tile
    const int quad = lane >> 4;  // k-group / row-group

    const int sblk = blockIdx.x & 7;
    const int qblk = blockIdx.x >> 3;
    const int s0 = sblk * SCHUNK;
    const int q0 = qblk * QPER;

    const int srow = t & 127;   // this thread's support row within chunk
    const int dhalf = t >> 7;   // 0: d in [0,64), 1: d in [64,128)

    // ---- one-time: support slice -> registers (f16), 64 values/thread ----
    f16x8 sup8[8];
    {
        const float* sp = support_x + (size_t)(s0 + srow) * DD + dhalf * 64;
#pragma unroll
        for (int g = 0; g < 8; ++g) {
            float4 v0 = *(const float4*)(sp + 8 * g);
            float4 v1 = *(const float4*)(sp + 8 * g + 4);
            f16x8 s;
            s[0] = (_Float16)v0.x; s[1] = (_Float16)v0.y;
            s[2] = (_Float16)v0.z; s[3] = (_Float16)v0.w;
            s[4] = (_Float16)v1.x; s[5] = (_Float16)v1.y;
            s[6] = (_Float16)v1.z; s[7] = (_Float16)v1.w;
            sup8[g] = s;
        }
    }

    if (t < SCHUNK) labels[t] = support_y[s0 + t];

    // ---- one-time: W1 B-fragments + per-lane b1/W2 ----
    // B[k=quad*8+e][n=c] for h-subtile j, k-step k  -> W1[j*16+c][k*32+quad*8+e]
    f16x8 bfrag[4][4];
    float b1h[4], w2h[4];
#pragma unroll
    for (int j = 0; j < 4; ++j) {
        const int h = j * 16 + c;
#pragma unroll
        for (int k = 0; k < 4; ++k) {
            const float* wp = W1 + h * DD + k * 32 + quad * 8;
            float4 v0 = *(const float4*)(wp);
            float4 v1 = *(const float4*)(wp + 4);
            f16x8 s;
            s[0] = (_Float16)v0.x; s[1] = (_Float16)v0.y;
            s[2] = (_Float16)v0.z; s[3] = (_Float16)v0.w;
            s[4] = (_Float16)v1.x; s[5] = (_Float16)v1.y;
            s[6] = (_Float16)v1.z; s[7] = (_Float16)v1.w;
            bfrag[j][k] = s;
        }
        b1h[j] = b1[h];
        w2h[j] = W2[h];
    }

    // diff write base for this thread (16B-aligned chunks)
    _Float16* wbase = diff + (srow >> 4) * 2048 + (srow & 15) * 8 + dhalf * 1024;

    for (int qq = 0; qq < QPER; ++qq) {
        const int q = q0 + qq;

        // stage query row (f16) + reset class buckets
        if (t < 32) {
            float4 v = *(const float4*)(query_x + (size_t)q * DD + 4 * t);
            f16x2 a; a[0] = (_Float16)v.x; a[1] = (_Float16)v.y;
            f16x2 b; b[0] = (_Float16)v.z; b[1] = (_Float16)v.w;
            *(f16x2*)(qrow + 4 * t) = a;
            *(f16x2*)(qrow + 4 * t + 2) = b;
        }
        if (t < NWAY) cls[t] = 0.f;
        __syncthreads();  // B1: qrow ready, cls reset

        // ---- |support - query| -> LDS in fragment order ----
        {
            const f16x8* q8 = (const f16x8*)(qrow + dhalf * 64);
#pragma unroll
            for (int g = 0; g < 8; ++g) {
                f16x8 dv = sup8[g] - q8[g];
                union { f16x8 f; u16x8 u; } cv;
                cv.f = dv;
                cv.u = cv.u & (unsigned short)0x7fffu;  // abs
                *(f16x8*)(wbase + g * 128) = cv.f;
            }
        }
        __syncthreads();  // B2: diff tile ready

        // ---- MFMA: wave owns s-subtiles {2*wave, 2*wave+1}, all 4 h-subtiles ----
        f32x4 acc[2][4];
#pragma unroll
        for (int ii = 0; ii < 2; ++ii)
#pragma unroll
            for (int j = 0; j < 4; ++j)
                acc[ii][j] = (f32x4){0.f, 0.f, 0.f, 0.f};

#pragma unroll
        for (int k = 0; k < 4; ++k) {
            f16x8 af0 = *(const f16x8*)(diff + (2 * wave + 0) * 2048 + (k * 4 + quad) * 128 + c * 8);
            f16x8 af1 = *(const f16x8*)(diff + (2 * wave + 1) * 2048 + (k * 4 + quad) * 128 + c * 8);
#pragma unroll
            for (int j = 0; j < 4; ++j) {
                acc[0][j] = __builtin_amdgcn_mfma_f32_16x16x32_f16(af0, bfrag[j][k], acc[0][j], 0, 0, 0);
                acc[1][j] = __builtin_amdgcn_mfma_f32_16x16x32_f16(af1, bfrag[j][k], acc[1][j], 0, 0, 0);
            }
        }

        // ---- epilogue: sim(s) = sum_h relu(acc + b1[h]) * W2[h], class-bucket ----
#pragma unroll
        for (int ii = 0; ii < 2; ++ii) {
#pragma unroll
            for (int r = 0; r < 4; ++r) {
                float val = 0.f;
#pragma unroll
                for (int j = 0; j < 4; ++j) {
                    float hv = acc[ii][j][r] + b1h[j];
                    hv = fmaxf(hv, 0.f);
                    val = fmaf(hv, w2h[j], val);
                }
                // sum over the 16 lanes (h columns) of this quad-group
                val += __shfl_xor(val, 1);
                val += __shfl_xor(val, 2);
                val += __shfl_xor(val, 4);
                val += __shfl_xor(val, 8);
                if (c == 0) {
                    const int s_local = (2 * wave + ii) * 16 + quad * 4 + r;
                    atomicAdd(&cls[labels[s_local]], val);
                }
            }
        }
        __syncthreads();  // B3: cls complete, diff reads drained

        if (t < NWAY) atomicAdd(&class_sums[q * NWAY + t], cls[t]);
    }
}

// Finalize: counts, per-class mean, log_softmax. Grid 8 x 128 threads.
__global__ void siamese_finalize(
    const int* __restrict__ support_y,
    const float* __restrict__ class_sums,
    float* __restrict__ out)
{
    __shared__ float cnt[NWAY];
    const int t = threadIdx.x;
    if (t < NWAY) cnt[t] = 0.f;
    __syncthreads();
#pragma unroll
    for (int i = 0; i < NS / 128; ++i)
        atomicAdd(&cnt[support_y[t * (NS / 128) + i]], 1.0f);
    __syncthreads();

    const int q = blockIdx.x * 128 + t;
    float lg[NWAY];
    float mx = -1e30f;
#pragma unroll
    for (int k = 0; k < NWAY; ++k) {
        lg[k] = class_sums[q * NWAY + k] / cnt[k];
        mx = fmaxf(mx, lg[k]);
    }
    float ss = 0.f;
#pragma unroll
    for (int k = 0; k < NWAY; ++k) ss += expf(lg[k] - mx);
    const float lse = mx + logf(ss);
#pragma unroll
    for (int k = 0; k < NWAY; ++k) out[q * NWAY + k] = lg[k] - lse;
}

extern "C" void kernel_launch(void* const* d_in, const int* in_sizes, int n_in,
                              void* d_out, int out_size, void* d_ws, size_t ws_size,
                              hipStream_t stream) {
    const float* support_x = (const float*)d_in[0];
    const int* support_y   = (const int*)d_in[1];
    const float* query_x   = (const float*)d_in[2];
    // d_in[3] = n_way (scalar, fixed at 8) — unused
    const float* W1 = (const float*)d_in[4];
    const float* b1 = (const float*)d_in[5];
    const float* W2 = (const float*)d_in[6];
    // d_in[7] = b2 — dropped (uniform logit shift, log_softmax-invariant)

    float* class_sums = (float*)d_ws;  // [NQ][NWAY] fp32, 32 KB
    hipMemsetAsync(class_sums, 0, NQ * NWAY * sizeof(float), stream);

    siamese_main<<<dim3((NS / SCHUNK) * (NQ / QPER)), dim3(256), 0, stream>>>(
        support_x, support_y, query_x, W1, b1, W2, class_sums);
    siamese_finalize<<<dim3(NQ / 128), dim3(128), 0, stream>>>(
        support_y, class_sums, (float*)d_out);
}